// Round 10
// baseline (349.372 us; speedup 1.0000x reference)
//
#include <hip/hip_runtime.h>
#include <hip/hip_bf16.h>

#define LRELU_SLOPE 0.2f

typedef __attribute__((ext_vector_type(8))) short short8;
typedef __attribute__((ext_vector_type(4))) float f32x4;

__device__ __forceinline__ unsigned short bf16r(float f) {
    unsigned int u = __builtin_bit_cast(unsigned int, f);
    u += 0x7fffu + ((u >> 16) & 1u);   // RNE
    return (unsigned short)(u >> 16);
}
__device__ __forceinline__ float bf2f(unsigned short u) {
    return __builtin_bit_cast(float, (unsigned int)u << 16);
}

// ---------------- fused preamble: all W -> WT bf16 transposed + edge count ----------------

#define WTOT 108544  // 65536 + 32768 + 8192 + 2048

__global__ void k_pre(const float* __restrict__ Wa, const float* __restrict__ Wb,
                      const float* __restrict__ Wc, const float* __restrict__ Wd,
                      unsigned short* __restrict__ Ta, unsigned short* __restrict__ Tb,
                      unsigned short* __restrict__ Tc, unsigned short* __restrict__ Td,
                      const int* __restrict__ ei, int* __restrict__ cnt, int E, int N) {
    int gid = blockIdx.x * blockDim.x + threadIdx.x;
    if (gid < WTOT) {
        int id = gid;
        const float* W; unsigned short* T; int K, Nc;
        if (id < 65536)       { W = Wa; T = Ta; K = 256; Nc = 256; }
        else if (id < 98304)  { id -= 65536;  W = Wb; T = Tb; K = 256; Nc = 128; }
        else if (id < 106496) { id -= 98304;  W = Wc; T = Tc; K = 128; Nc = 64; }
        else                  { id -= 106496; W = Wd; T = Td; K = 64;  Nc = 32; }
        int n = id / K, k = id % K;
        T[id] = bf16r(W[(long)k * Nc + n]);
        return;
    }
    int e = gid - WTOT;
    if (e >= E + N) return;
    int dst = (e < E) ? ei[E + e] : (e - E);
    atomicAdd(&cnt[dst], 1);
}

// ---------------- CSR scan + scatter ----------------

__global__ void k_scan_blk(const int* __restrict__ cnt, int* __restrict__ offs,
                           int* __restrict__ bsum, int N) {
    __shared__ int temp[1024];
    int t = threadIdx.x;
    int gi = blockIdx.x * 1024 + t;
    int v = (gi < N) ? cnt[gi] : 0;
    temp[t] = v;
    __syncthreads();
    for (int o = 1; o < 1024; o <<= 1) {
        int x = (t >= o) ? temp[t - o] : 0;
        __syncthreads();
        temp[t] += x;
        __syncthreads();
    }
    if (gi < N) offs[gi] = temp[t] - v;
    if (t == 1023) bsum[blockIdx.x] = temp[1023];
}

__global__ void k_scan(const int* __restrict__ cnt, int* __restrict__ offs, int N) {
    __shared__ int temp[1024];
    __shared__ int carry_s;
    int t = threadIdx.x;
    if (t == 0) carry_s = 0;
    __syncthreads();
    for (int base = 0; base < N; base += 1024) {
        int v = (base + t < N) ? cnt[base + t] : 0;
        temp[t] = v;
        __syncthreads();
        for (int o = 1; o < 1024; o <<= 1) {
            int x = (t >= o) ? temp[t - o] : 0;
            __syncthreads();
            temp[t] += x;
            __syncthreads();
        }
        int incl = temp[t];
        int carry = carry_s;
        if (base + t < N) offs[base + t] = carry + incl - v;
        __syncthreads();
        if (t == 1023) carry_s = carry + temp[1023];
        __syncthreads();
    }
    if (t == 0) offs[N] = carry_s;
}

__global__ void k_scan_add(int* __restrict__ offs, const int* __restrict__ bpre,
                           int* __restrict__ wp, int N, int nb) {
    int gi = blockIdx.x * blockDim.x + threadIdx.x;
    if (gi < N) {
        int v = offs[gi] + bpre[gi >> 10];
        offs[gi] = v;
        wp[gi] = v;
    } else if (gi == N) {
        offs[N] = bpre[nb];
    }
}

__global__ void k_scatter(const int* __restrict__ ei, int* __restrict__ wp,
                          int* __restrict__ adj, int E, int N) {
    int e = blockIdx.x * blockDim.x + threadIdx.x;
    if (e >= E + N) return;
    int srcn = (e < E) ? ei[e] : (e - E);
    int dst  = (e < E) ? ei[E + e] : (e - E);
    int pos = atomicAdd(&wp[dst], 1);
    adj[pos] = srcn;
}

// ---------------- MFMA GEMM + fused s/d scores ----------------
// 64-row tile (4 waves x 16 rows) for occupancy, register prefetch across the
// barrier so global latency overlaps MFMA of the previous K-step.

#define PSTR 40  // K-loop LDS row stride (shorts)

template<int BN, bool F32A>
__global__ __launch_bounds__(256) void k_mgemm(const void* __restrict__ Ain,
                                               const unsigned short* __restrict__ WT,
                                               unsigned short* __restrict__ Cb,
                                               const float* __restrict__ a_src,
                                               const float* __restrict__ a_dst,
                                               float* __restrict__ sbuf,
                                               float* __restrict__ dbuf,
                                               int M, int Nc, int K, int H) {
    constexpr int NBF = BN / 16;           // B fragments per wave
    constexpr int BCH = BN / 64;           // B staging chunks per thread
    constexpr int SP  = BN + 8;            // epilogue LDS stride (shorts)
    constexpr int CPR = BN / 32;           // 32-col chunks per row
    constexpr int STAGE = 64 * PSTR + BN * PSTR;
    constexpr int EPIL  = 64 * SP;
    constexpr int LBSZ  = STAGE > EPIL ? STAGE : EPIL;
    __shared__ __align__(16) unsigned short LB[LBSZ];
    unsigned short* As = LB;
    unsigned short* Bs = LB + 64 * PSTR;

    int t = threadIdx.x;
    int wv = t >> 6, l = t & 63;
    int bm = blockIdx.y * 64, bn = blockIdx.x * BN;

    f32x4 acc[NBF];
#pragma unroll
    for (int j = 0; j < NBF; ++j) acc[j] = (f32x4){0.f, 0.f, 0.f, 0.f};

    int ar = t >> 2, akc = t & 3;          // A: 64 rows x 4 k-chunks
    int grA = min(bm + ar, M - 1);
    int bc[BCH], gcB[BCH];
#pragma unroll
    for (int i = 0; i < BCH; ++i) {
        bc[i] = (t >> 2) + i * 64;
        gcB[i] = min(bn + bc[i], Nc - 1);
    }

    int row_in = l & 15, quad = l >> 4;
    const short8* apf = (const short8*)&As[(wv * 16 + row_in) * PSTR + quad * 8];
    const short8* bpf[NBF];
#pragma unroll
    for (int f = 0; f < NBF; ++f)
        bpf[f] = (const short8*)&Bs[(f * 16 + row_in) * PSTR + quad * 8];

    const float* Af = (const float*)Ain;
    const unsigned short* Ab = (const unsigned short*)Ain;

    // prefetch registers (current + next)
    float4 af0, af1, af0n, af1n;
    short8 ab8, ab8n;
    short8 bb[BCH], bbn[BCH];

    // prologue: fetch k0 = 0
    if constexpr (F32A) {
        const float4* p = (const float4*)&Af[(long)grA * K + akc * 8];
        af0 = p[0]; af1 = p[1];
    } else {
        ab8 = *(const short8*)&Ab[(long)grA * K + akc * 8];
    }
#pragma unroll
    for (int i = 0; i < BCH; ++i)
        bb[i] = *(const short8*)&WT[(long)gcB[i] * K + akc * 8];

    for (int k0 = 0; k0 < K; k0 += 32) {
        // LDS write of current regs
        short8 av;
        if constexpr (F32A) {
            av[0] = (short)bf16r(af0.x); av[1] = (short)bf16r(af0.y);
            av[2] = (short)bf16r(af0.z); av[3] = (short)bf16r(af0.w);
            av[4] = (short)bf16r(af1.x); av[5] = (short)bf16r(af1.y);
            av[6] = (short)bf16r(af1.z); av[7] = (short)bf16r(af1.w);
        } else {
            av = ab8;
        }
        *(short8*)&As[ar * PSTR + akc * 8] = av;
#pragma unroll
        for (int i = 0; i < BCH; ++i)
            *(short8*)&Bs[bc[i] * PSTR + akc * 8] = bb[i];
        __syncthreads();

        // issue next K-step's global loads before the MFMA of this step
        int kn = k0 + 32;
        if (kn < K) {
            if constexpr (F32A) {
                const float4* p = (const float4*)&Af[(long)grA * K + kn + akc * 8];
                af0n = p[0]; af1n = p[1];
            } else {
                ab8n = *(const short8*)&Ab[(long)grA * K + kn + akc * 8];
            }
#pragma unroll
            for (int i = 0; i < BCH; ++i)
                bbn[i] = *(const short8*)&WT[(long)gcB[i] * K + kn + akc * 8];
        }

        short8 a0 = *apf;
#pragma unroll
        for (int f = 0; f < NBF; ++f) {
            short8 b = *bpf[f];
            acc[f] = __builtin_amdgcn_mfma_f32_16x16x32_bf16(a0, b, acc[f], 0, 0, 0);
        }
        __syncthreads();

        af0 = af0n; af1 = af1n; ab8 = ab8n;
#pragma unroll
        for (int i = 0; i < BCH; ++i) bb[i] = bbn[i];
    }

    // ---- epilogue: LDS repack (bf16) -> coalesced stores + fused s/d ----
    // C/D layout: col = ct*16 + (lane&15), row (within wave tile) = quad*4 + reg
#pragma unroll
    for (int r = 0; r < 4; ++r)
#pragma unroll
        for (int ct = 0; ct < NBF; ++ct)
            LB[(wv * 16 + quad * 4 + r) * SP + ct * 16 + row_in] = bf16r(acc[ct][r]);
    __syncthreads();

    int rr = t / CPR, cc = t % CPR;
    if (rr < 64) {
        int grow = bm + rr;
        int colb = bn + cc * 32;
        if (grow < M && colb < Nc) {
            const unsigned short* ep = &LB[rr * SP + cc * 32];
            short8 v0 = *(const short8*)(ep);
            short8 v1 = *(const short8*)(ep + 8);
            short8 v2 = *(const short8*)(ep + 16);
            short8 v3 = *(const short8*)(ep + 24);
            unsigned short* cp = &Cb[(long)grow * Nc + colb];
            *(short8*)(cp)      = v0;
            *(short8*)(cp + 8)  = v1;
            *(short8*)(cp + 16) = v2;
            *(short8*)(cp + 24) = v3;
            int hd = colb >> 5;   // 32 channels per head
            const float* ap = a_src + hd * 32;
            const float* dp = a_dst + hd * 32;
            float ss = 0.f, dd = 0.f;
#pragma unroll
            for (int u = 0; u < 8; ++u) {
                float va = bf2f((unsigned short)v0[u]); ss += va * ap[u];      dd += va * dp[u];
                float vb = bf2f((unsigned short)v1[u]); ss += vb * ap[8 + u];  dd += vb * dp[8 + u];
                float vc = bf2f((unsigned short)v2[u]); ss += vc * ap[16 + u]; dd += vc * dp[16 + u];
                float vd = bf2f((unsigned short)v3[u]); ss += vd * ap[24 + u]; dd += vd * dp[24 + u];
            }
            sbuf[(long)grow * H + hd] = ss;
            dbuf[(long)grow * H + hd] = dd;
        }
    }
}

// ---------------- fused aggregate: max-free softmax, single pass ----------------
// one thread per (node, head, c/8). ACT=1: elu -> bf16 out (next GEMM input).
// ACT=0: final layer (H==1) -> log_softmax via quad shuffles -> fp32 d_out.

template<int ACT>
__global__ void k_aggf(const unsigned short* __restrict__ h, const float* __restrict__ s,
                       const float* __restrict__ dsc, const int* __restrict__ offs,
                       const int* __restrict__ adj, const float* __restrict__ bias,
                       unsigned short* __restrict__ out16, float* __restrict__ out32,
                       int N, int H) {
    const int C8 = 4;
    long tid = (long)blockIdx.x * blockDim.x + threadIdx.x;
    int HC8 = H * C8;
    if (tid >= (long)N * HC8) return;
    int c8 = (int)(tid % C8);
    int hh = (int)((tid / C8) % H);
    int n  = (int)(tid / HC8);
    int beg = offs[n], end = offs[n + 1];
    float dn = dsc[n * H + hh];
    int HC = HC8 * 8;
    int coff = hh * 32 + c8 * 8;

    float denom = 0.f;
    float acc[8];
#pragma unroll
    for (int u = 0; u < 8; ++u) acc[u] = 0.f;

    for (int j = beg; j < end; ++j) {
        int sn = adj[j];
        float e = s[sn * H + hh] + dn;
        e = e > 0.f ? e : LRELU_SLOPE * e;
        float w = __expf(fminf(e, 80.f));
        short8 hv = *(const short8*)(h + (size_t)sn * HC + coff);
        denom += w;
#pragma unroll
        for (int u = 0; u < 8; ++u)
            acc[u] += w * bf2f((unsigned short)hv[u]);
    }

    float inv = 1.0f / denom;
    float o[8];
#pragma unroll
    for (int u = 0; u < 8; ++u) o[u] = acc[u] * inv + bias[coff + u];

    if (ACT == 1) {
        short8 pk;
#pragma unroll
        for (int u = 0; u < 8; ++u) {
            float v = o[u] > 0.f ? o[u] : (__expf(o[u]) - 1.f);
            pk[u] = (short)bf16r(v);
        }
        *(short8*)(out16 + tid * 8) = pk;
    } else {
        float m = o[0];
#pragma unroll
        for (int u = 1; u < 8; ++u) m = fmaxf(m, o[u]);
        m = fmaxf(m, __shfl_xor(m, 1));
        m = fmaxf(m, __shfl_xor(m, 2));
        float ssum = 0.f;
#pragma unroll
        for (int u = 0; u < 8; ++u) ssum += __expf(o[u] - m);
        ssum += __shfl_xor(ssum, 1);
        ssum += __shfl_xor(ssum, 2);
        float lse = m + __logf(ssum);
        float4 lo = {o[0] - lse, o[1] - lse, o[2] - lse, o[3] - lse};
        float4 hi = {o[4] - lse, o[5] - lse, o[6] - lse, o[7] - lse};
        *(float4*)(out32 + tid * 8)     = lo;
        *(float4*)(out32 + tid * 8 + 4) = hi;
    }
}

// ---------------- host ----------------

static inline size_t align_up(size_t x) { return (x + 255) & ~(size_t)255; }

extern "C" void kernel_launch(void* const* d_in, const int* in_sizes, int n_in,
                              void* d_out, int out_size, void* d_ws, size_t ws_size,
                              hipStream_t stream) {
    const float* x   = (const float*)d_in[0];
    const int*   ei  = (const int*)d_in[1];

    const int N = in_sizes[0] / 256;   // 50000
    const int E = in_sizes[1] / 2;     // 400000
    const int ET = E + N;
    const int NB = (N + 1023) / 1024;

    size_t off = 0;
    char* ws = (char*)d_ws;
    auto take = [&](size_t bytes) { char* p = ws + off; off += align_up(bytes); return p; };
    int*   offs  = (int*)take((size_t)(N + 1) * 4);
    int*   wp    = (int*)take((size_t)N * 4);
    int*   adj   = (int*)take((size_t)ET * 4);
    int*   bsum  = (int*)take((size_t)(NB + 1) * 4);
    int*   bpre  = (int*)take((size_t)(NB + 1) * 4);
    float* sbuf  = (float*)take((size_t)N * 8 * 4);
    float* dbuf  = (float*)take((size_t)N * 8 * 4);
    unsigned short* Xb = (unsigned short*)take((size_t)N * 256 * 2);  // activations (bf16)
    unsigned short* Yb = (unsigned short*)take((size_t)N * 256 * 2);  // h (GEMM out, bf16)
    unsigned short* WT0 = (unsigned short*)take((size_t)256 * 256 * 2);
    unsigned short* WT1 = (unsigned short*)take((size_t)256 * 128 * 2);
    unsigned short* WT2 = (unsigned short*)take((size_t)128 * 64 * 2);
    unsigned short* WT3 = (unsigned short*)take((size_t)64 * 32 * 2);
    (void)ws_size;

    // ---- preamble + CSR build ----
    hipMemsetAsync(wp, 0, (size_t)N * 4, stream);
    {
        long tot = WTOT + ET;
        k_pre<<<(int)((tot + 255) / 256), 256, 0, stream>>>(
            (const float*)d_in[2], (const float*)d_in[6], (const float*)d_in[10],
            (const float*)d_in[14], WT0, WT1, WT2, WT3, ei, wp, E, N);
        k_scan_blk<<<NB, 1024, 0, stream>>>(wp, offs, bsum, N);
        k_scan<<<1, 1024, 0, stream>>>(bsum, bpre, NB);
        k_scan_add<<<(N + 256) / 256, 256, 0, stream>>>(offs, bpre, wp, N, NB);
        k_scatter<<<(ET + 255) / 256, 256, 0, stream>>>(ei, wp, adj, E, N);
    }

    struct Layer { const float* as; const float* ad; const float* b;
                   const unsigned short* WT; int Fin; int H; };
    Layer layers[4] = {
        {(const float*)d_in[3],  (const float*)d_in[4],  (const float*)d_in[5],  WT0, 256, 8},
        {(const float*)d_in[7],  (const float*)d_in[8],  (const float*)d_in[9],  WT1, 256, 4},
        {(const float*)d_in[11], (const float*)d_in[12], (const float*)d_in[13], WT2, 128, 2},
        {(const float*)d_in[15], (const float*)d_in[16], (const float*)d_in[17], WT3,  64, 1},
    };

    for (int li = 0; li < 4; ++li) {
        Layer& L = layers[li];
        int HC = L.H * 32;
        int K = L.Fin;

        // GEMM + fused s/d (64-row tiles)
        if (li == 0) {
            dim3 grd((HC + 127) / 128, (N + 63) / 64);
            k_mgemm<128, true><<<grd, 256, 0, stream>>>(x, L.WT, Yb, L.as, L.ad,
                                                        sbuf, dbuf, N, HC, K, L.H);
        } else if (HC >= 128) {
            dim3 grd(HC / 128, (N + 63) / 64);
            k_mgemm<128, false><<<grd, 256, 0, stream>>>(Xb, L.WT, Yb, L.as, L.ad,
                                                         sbuf, dbuf, N, HC, K, L.H);
        } else {
            dim3 grd((HC + 63) / 64, (N + 63) / 64);
            k_mgemm<64, false><<<grd, 256, 0, stream>>>(Xb, L.WT, Yb, L.as, L.ad,
                                                        sbuf, dbuf, N, HC, K, L.H);
        }
        // aggregate (+elu->bf16 for layers 0-2; +log_softmax->d_out for layer 3)
        {
            long total = (long)N * L.H * 4;
            int nb = (int)((total + 255) / 256);
            if (li < 3)
                k_aggf<1><<<nb, 256, 0, stream>>>(Yb, sbuf, dbuf, offs, adj, L.b,
                                                  Xb, nullptr, N, L.H);
            else
                k_aggf<0><<<nb, 256, 0, stream>>>(Yb, sbuf, dbuf, offs, adj, L.b,
                                                  nullptr, (float*)d_out, N, L.H);
        }
    }
}

// Round 11
// 340.179 us; speedup vs baseline: 1.0270x; 1.0270x over previous
//
#include <hip/hip_runtime.h>
#include <hip/hip_bf16.h>

#define LRELU_SLOPE 0.2f

typedef __attribute__((ext_vector_type(8))) short short8;
typedef __attribute__((ext_vector_type(4))) float f32x4;

__device__ __forceinline__ unsigned short bf16r(float f) {
    unsigned int u = __builtin_bit_cast(unsigned int, f);
    u += 0x7fffu + ((u >> 16) & 1u);   // RNE
    return (unsigned short)(u >> 16);
}
__device__ __forceinline__ float bf2f(unsigned short u) {
    return __builtin_bit_cast(float, (unsigned int)u << 16);
}

// ---------------- fused preamble: all W -> WT bf16 transposed + edge count ----------------

#define WTOT 108544  // 65536 + 32768 + 8192 + 2048

__global__ void k_pre(const float* __restrict__ Wa, const float* __restrict__ Wb,
                      const float* __restrict__ Wc, const float* __restrict__ Wd,
                      unsigned short* __restrict__ Ta, unsigned short* __restrict__ Tb,
                      unsigned short* __restrict__ Tc, unsigned short* __restrict__ Td,
                      const int* __restrict__ ei, int* __restrict__ cnt, int E, int N) {
    int gid = blockIdx.x * blockDim.x + threadIdx.x;
    if (gid < WTOT) {
        int id = gid;
        const float* W; unsigned short* T; int K, Nc;
        if (id < 65536)       { W = Wa; T = Ta; K = 256; Nc = 256; }
        else if (id < 98304)  { id -= 65536;  W = Wb; T = Tb; K = 256; Nc = 128; }
        else if (id < 106496) { id -= 98304;  W = Wc; T = Tc; K = 128; Nc = 64; }
        else                  { id -= 106496; W = Wd; T = Td; K = 64;  Nc = 32; }
        int n = id / K, k = id % K;
        T[id] = bf16r(W[(long)k * Nc + n]);
        return;
    }
    int e = gid - WTOT;
    if (e >= E + N) return;
    int dst = (e < E) ? ei[E + e] : (e - E);
    atomicAdd(&cnt[dst], 1);
}

// ---------------- CSR scan + scatter ----------------

__global__ void k_scan_blk(const int* __restrict__ cnt, int* __restrict__ offs,
                           int* __restrict__ bsum, int N) {
    __shared__ int temp[1024];
    int t = threadIdx.x;
    int gi = blockIdx.x * 1024 + t;
    int v = (gi < N) ? cnt[gi] : 0;
    temp[t] = v;
    __syncthreads();
    for (int o = 1; o < 1024; o <<= 1) {
        int x = (t >= o) ? temp[t - o] : 0;
        __syncthreads();
        temp[t] += x;
        __syncthreads();
    }
    if (gi < N) offs[gi] = temp[t] - v;
    if (t == 1023) bsum[blockIdx.x] = temp[1023];
}

__global__ void k_scan(const int* __restrict__ cnt, int* __restrict__ offs, int N) {
    __shared__ int temp[1024];
    __shared__ int carry_s;
    int t = threadIdx.x;
    if (t == 0) carry_s = 0;
    __syncthreads();
    for (int base = 0; base < N; base += 1024) {
        int v = (base + t < N) ? cnt[base + t] : 0;
        temp[t] = v;
        __syncthreads();
        for (int o = 1; o < 1024; o <<= 1) {
            int x = (t >= o) ? temp[t - o] : 0;
            __syncthreads();
            temp[t] += x;
            __syncthreads();
        }
        int incl = temp[t];
        int carry = carry_s;
        if (base + t < N) offs[base + t] = carry + incl - v;
        __syncthreads();
        if (t == 1023) carry_s = carry + temp[1023];
        __syncthreads();
    }
    if (t == 0) offs[N] = carry_s;
}

__global__ void k_scan_add(int* __restrict__ offs, const int* __restrict__ bpre,
                           int* __restrict__ wp, int N, int nb) {
    int gi = blockIdx.x * blockDim.x + threadIdx.x;
    if (gi < N) {
        int v = offs[gi] + bpre[gi >> 10];
        offs[gi] = v;
        wp[gi] = v;
    } else if (gi == N) {
        offs[N] = bpre[nb];
    }
}

__global__ void k_scatter(const int* __restrict__ ei, int* __restrict__ wp,
                          int* __restrict__ adj, int E, int N) {
    int e = blockIdx.x * blockDim.x + threadIdx.x;
    if (e >= E + N) return;
    int srcn = (e < E) ? ei[e] : (e - E);
    int dst  = (e < E) ? ei[E + e] : (e - E);
    int pos = atomicAdd(&wp[dst], 1);
    adj[pos] = srcn;
}

// ---------------- MFMA GEMM + fused s/d scores (barrier-free K-loop) ----------------
// B (weights) staged in LDS ONCE for the whole K; A-frags loaded global->reg
// directly, ALL K-steps issued upfront (deep MLP, pays HBM latency once).
// Per-wave 16xBN tile; block = 4 waves = 64 rows x BN cols. No sync in K-loop.

template<int BN, int KT, bool F32A>
__global__ __launch_bounds__(256) void k_mgemm(const void* __restrict__ Ain,
                                               const unsigned short* __restrict__ WT,
                                               unsigned short* __restrict__ Cb,
                                               const float* __restrict__ a_src,
                                               const float* __restrict__ a_dst,
                                               float* __restrict__ sbuf,
                                               float* __restrict__ dbuf,
                                               int M, int Nc, int H) {
    constexpr int KITER = KT / 32;       // K-steps (2..8)
    constexpr int KS  = KT + 8;          // B LDS col stride (shorts) -> 2-way conflicts only
    constexpr int NBF = BN / 16;         // B fragments per wave
    constexpr int CPR = BN / 32;         // 32-col chunks per row (epilogue)
    constexpr int SP  = BN + 8;          // epilogue LDS row stride
    constexpr int STAGE = BN * KS;
    constexpr int EPIL  = 64 * SP;
    constexpr int LBSZ  = STAGE > EPIL ? STAGE : EPIL;
    __shared__ __align__(16) unsigned short LB[LBSZ];

    int t = threadIdx.x;
    int wv = t >> 6, l = t & 63;
    int row_in = l & 15, quad = l >> 4;
    int bm = blockIdx.y * 64, bn = blockIdx.x * BN;

    // ---- issue ALL A-frag loads upfront (per-lane own fragment) ----
    int grA = min(bm + wv * 16 + row_in, M - 1);
    const float* Af = (const float*)Ain;
    const unsigned short* Ab = (const unsigned short*)Ain;
    float4 af0[KITER], af1[KITER];
    short8 areg[KITER];
    if constexpr (F32A) {
#pragma unroll
        for (int ki = 0; ki < KITER; ++ki) {
            const float4* p = (const float4*)&Af[(long)grA * KT + ki * 32 + quad * 8];
            af0[ki] = p[0];
            af1[ki] = p[1];
        }
    } else {
#pragma unroll
        for (int ki = 0; ki < KITER; ++ki)
            areg[ki] = *(const short8*)&Ab[(long)grA * KT + ki * 32 + quad * 8];
    }

    // ---- cooperative B stage (whole K), single barrier ----
    constexpr int PER = BN * (KT / 8) / 256;   // 16B chunks per thread (>=1)
#pragma unroll
    for (int i = 0; i < PER; ++i) {
        int ch = t + i * 256;
        int col = ch / (KT / 8);
        int kc  = ch % (KT / 8);
        int gcol = min(bn + col, Nc - 1);
        *(short8*)&LB[col * KS + kc * 8] = *(const short8*)&WT[(long)gcol * KT + kc * 8];
    }
    __syncthreads();

    f32x4 acc[NBF];
#pragma unroll
    for (int j = 0; j < NBF; ++j) acc[j] = (f32x4){0.f, 0.f, 0.f, 0.f};

    // ---- K loop: no barriers, B from LDS, A from prefetched regs ----
#pragma unroll
    for (int ki = 0; ki < KITER; ++ki) {
        short8 av;
        if constexpr (F32A) {
            float4 f0 = af0[ki], f1 = af1[ki];
            av[0] = (short)bf16r(f0.x); av[1] = (short)bf16r(f0.y);
            av[2] = (short)bf16r(f0.z); av[3] = (short)bf16r(f0.w);
            av[4] = (short)bf16r(f1.x); av[5] = (short)bf16r(f1.y);
            av[6] = (short)bf16r(f1.z); av[7] = (short)bf16r(f1.w);
        } else {
            av = areg[ki];
        }
#pragma unroll
        for (int f = 0; f < NBF; ++f) {
            short8 bv = *(const short8*)&LB[(f * 16 + row_in) * KS + ki * 32 + quad * 8];
            acc[f] = __builtin_amdgcn_mfma_f32_16x16x32_bf16(av, bv, acc[f], 0, 0, 0);
        }
    }
    __syncthreads();   // before LDS reuse for epilogue

    // ---- epilogue: LDS repack (bf16) -> coalesced stores + fused s/d ----
    // C/D layout: col = f*16 + (lane&15), row (in wave tile) = quad*4 + reg
#pragma unroll
    for (int r = 0; r < 4; ++r)
#pragma unroll
        for (int f = 0; f < NBF; ++f)
            LB[(wv * 16 + quad * 4 + r) * SP + f * 16 + row_in] = bf16r(acc[f][r]);
    __syncthreads();

    int rr = t / CPR, cc = t % CPR;
    if (rr < 64) {
        int grow = bm + rr;
        int colb = bn + cc * 32;
        if (grow < M && colb < Nc) {
            const unsigned short* ep = &LB[rr * SP + cc * 32];
            short8 v0 = *(const short8*)(ep);
            short8 v1 = *(const short8*)(ep + 8);
            short8 v2 = *(const short8*)(ep + 16);
            short8 v3 = *(const short8*)(ep + 24);
            unsigned short* cp = &Cb[(long)grow * Nc + colb];
            *(short8*)(cp)      = v0;
            *(short8*)(cp + 8)  = v1;
            *(short8*)(cp + 16) = v2;
            *(short8*)(cp + 24) = v3;
            int hd = colb >> 5;   // 32 channels per head
            const float* ap = a_src + hd * 32;
            const float* dp = a_dst + hd * 32;
            float ss = 0.f, dd = 0.f;
#pragma unroll
            for (int u = 0; u < 8; ++u) {
                float va = bf2f((unsigned short)v0[u]); ss += va * ap[u];      dd += va * dp[u];
                float vb = bf2f((unsigned short)v1[u]); ss += vb * ap[8 + u];  dd += vb * dp[8 + u];
                float vc = bf2f((unsigned short)v2[u]); ss += vc * ap[16 + u]; dd += vc * dp[16 + u];
                float vd = bf2f((unsigned short)v3[u]); ss += vd * ap[24 + u]; dd += vd * dp[24 + u];
            }
            sbuf[(long)grow * H + hd] = ss;
            dbuf[(long)grow * H + hd] = dd;
        }
    }
}

// ---------------- fused aggregate: max-free softmax, single pass ----------------
// one thread per (node, head, c/8). ACT=1: elu -> bf16 out (next GEMM input).
// ACT=0: final layer (H==1) -> log_softmax via quad shuffles -> fp32 d_out.

template<int ACT>
__global__ void k_aggf(const unsigned short* __restrict__ h, const float* __restrict__ s,
                       const float* __restrict__ dsc, const int* __restrict__ offs,
                       const int* __restrict__ adj, const float* __restrict__ bias,
                       unsigned short* __restrict__ out16, float* __restrict__ out32,
                       int N, int H) {
    const int C8 = 4;
    long tid = (long)blockIdx.x * blockDim.x + threadIdx.x;
    int HC8 = H * C8;
    if (tid >= (long)N * HC8) return;
    int c8 = (int)(tid % C8);
    int hh = (int)((tid / C8) % H);
    int n  = (int)(tid / HC8);
    int beg = offs[n], end = offs[n + 1];
    float dn = dsc[n * H + hh];
    int HC = HC8 * 8;
    int coff = hh * 32 + c8 * 8;

    float denom = 0.f;
    float acc[8];
#pragma unroll
    for (int u = 0; u < 8; ++u) acc[u] = 0.f;

    for (int j = beg; j < end; ++j) {
        int sn = adj[j];
        float e = s[sn * H + hh] + dn;
        e = e > 0.f ? e : LRELU_SLOPE * e;
        float w = __expf(fminf(e, 80.f));
        short8 hv = *(const short8*)(h + (size_t)sn * HC + coff);
        denom += w;
#pragma unroll
        for (int u = 0; u < 8; ++u)
            acc[u] += w * bf2f((unsigned short)hv[u]);
    }

    float inv = 1.0f / denom;
    float o[8];
#pragma unroll
    for (int u = 0; u < 8; ++u) o[u] = acc[u] * inv + bias[coff + u];

    if (ACT == 1) {
        short8 pk;
#pragma unroll
        for (int u = 0; u < 8; ++u) {
            float v = o[u] > 0.f ? o[u] : (__expf(o[u]) - 1.f);
            pk[u] = (short)bf16r(v);
        }
        *(short8*)(out16 + tid * 8) = pk;
    } else {
        float m = o[0];
#pragma unroll
        for (int u = 1; u < 8; ++u) m = fmaxf(m, o[u]);
        m = fmaxf(m, __shfl_xor(m, 1));
        m = fmaxf(m, __shfl_xor(m, 2));
        float ssum = 0.f;
#pragma unroll
        for (int u = 0; u < 8; ++u) ssum += __expf(o[u] - m);
        ssum += __shfl_xor(ssum, 1);
        ssum += __shfl_xor(ssum, 2);
        float lse = m + __logf(ssum);
        float4 lo = {o[0] - lse, o[1] - lse, o[2] - lse, o[3] - lse};
        float4 hi = {o[4] - lse, o[5] - lse, o[6] - lse, o[7] - lse};
        *(float4*)(out32 + tid * 8)     = lo;
        *(float4*)(out32 + tid * 8 + 4) = hi;
    }
}

// ---------------- host ----------------

static inline size_t align_up(size_t x) { return (x + 255) & ~(size_t)255; }

extern "C" void kernel_launch(void* const* d_in, const int* in_sizes, int n_in,
                              void* d_out, int out_size, void* d_ws, size_t ws_size,
                              hipStream_t stream) {
    const float* x   = (const float*)d_in[0];
    const int*   ei  = (const int*)d_in[1];

    const int N = in_sizes[0] / 256;   // 50000
    const int E = in_sizes[1] / 2;     // 400000
    const int ET = E + N;
    const int NB = (N + 1023) / 1024;

    size_t off = 0;
    char* ws = (char*)d_ws;
    auto take = [&](size_t bytes) { char* p = ws + off; off += align_up(bytes); return p; };
    int*   offs  = (int*)take((size_t)(N + 1) * 4);
    int*   wp    = (int*)take((size_t)N * 4);
    int*   adj   = (int*)take((size_t)ET * 4);
    int*   bsum  = (int*)take((size_t)(NB + 1) * 4);
    int*   bpre  = (int*)take((size_t)(NB + 1) * 4);
    float* sbuf  = (float*)take((size_t)N * 8 * 4);
    float* dbuf  = (float*)take((size_t)N * 8 * 4);
    unsigned short* Xb = (unsigned short*)take((size_t)N * 256 * 2);  // activations (bf16)
    unsigned short* Yb = (unsigned short*)take((size_t)N * 256 * 2);  // h (GEMM out, bf16)
    unsigned short* WT0 = (unsigned short*)take((size_t)256 * 256 * 2);
    unsigned short* WT1 = (unsigned short*)take((size_t)256 * 128 * 2);
    unsigned short* WT2 = (unsigned short*)take((size_t)128 * 64 * 2);
    unsigned short* WT3 = (unsigned short*)take((size_t)64 * 32 * 2);
    (void)ws_size;

    // ---- preamble + CSR build ----
    hipMemsetAsync(wp, 0, (size_t)N * 4, stream);
    {
        long tot = WTOT + ET;
        k_pre<<<(int)((tot + 255) / 256), 256, 0, stream>>>(
            (const float*)d_in[2], (const float*)d_in[6], (const float*)d_in[10],
            (const float*)d_in[14], WT0, WT1, WT2, WT3, ei, wp, E, N);
        k_scan_blk<<<NB, 1024, 0, stream>>>(wp, offs, bsum, N);
        k_scan<<<1, 1024, 0, stream>>>(bsum, bpre, NB);
        k_scan_add<<<(N + 256) / 256, 256, 0, stream>>>(offs, bpre, wp, N, NB);
        k_scatter<<<(ET + 255) / 256, 256, 0, stream>>>(ei, wp, adj, E, N);
    }

    const float* as_[4] = {(const float*)d_in[3], (const float*)d_in[7],
                           (const float*)d_in[11], (const float*)d_in[15]};
    const float* ad_[4] = {(const float*)d_in[4], (const float*)d_in[8],
                           (const float*)d_in[12], (const float*)d_in[16]};
    const float* b_[4]  = {(const float*)d_in[5], (const float*)d_in[9],
                           (const float*)d_in[13], (const float*)d_in[17]};
    int H_[4] = {8, 4, 2, 1};

    int gy = (N + 63) / 64;
    for (int li = 0; li < 4; ++li) {
        int H = H_[li];
        int HC = H * 32;

        // GEMM + fused s/d (barrier-free K-loop, per-layer template)
        if (li == 0) {
            k_mgemm<64, 256, true><<<dim3(4, gy), 256, 0, stream>>>(
                x, WT0, Yb, as_[0], ad_[0], sbuf, dbuf, N, 256, H);
        } else if (li == 1) {
            k_mgemm<64, 256, false><<<dim3(2, gy), 256, 0, stream>>>(
                Xb, WT1, Yb, as_[1], ad_[1], sbuf, dbuf, N, 128, H);
        } else if (li == 2) {
            k_mgemm<64, 128, false><<<dim3(1, gy), 256, 0, stream>>>(
                Xb, WT2, Yb, as_[2], ad_[2], sbuf, dbuf, N, 64, H);
        } else {
            k_mgemm<32, 64, false><<<dim3(1, gy), 256, 0, stream>>>(
                Xb, WT3, Yb, as_[3], ad_[3], sbuf, dbuf, N, 32, H);
        }
        // aggregate (+elu->bf16 for layers 0-2; +log_softmax->d_out for layer 3)
        {
            long total = (long)N * H * 4;
            int nb = (int)((total + 255) / 256);
            if (li < 3)
                k_aggf<1><<<nb, 256, 0, stream>>>(Yb, sbuf, dbuf, offs, adj, b_[li],
                                                  Xb, nullptr, N, H);
            else
                k_aggf<0><<<nb, 256, 0, stream>>>(Yb, sbuf, dbuf, offs, adj, b_[li],
                                                  nullptr, (float*)d_out, N, H);
        }
    }
}